// Round 8
// baseline (767.558 us; speedup 1.0000x reference)
//
#include <hip/hip_runtime.h>
#include <stdint.h>

typedef unsigned long long u64;
typedef unsigned int u32;
typedef unsigned short u16;
typedef unsigned char u8;
typedef signed char s8;

#define NB 4096

// ---------------- workspace layout (bytes) ----------------
#define WS_STATS 0          // long long[2304]  (stat*8+slot)
#define WS_CST   18432      // float[288]: (sc,sh) x3 stages
#define WS_W1Q   20480      // u32[240]
#define WS_W2P   24576      // u64[432]
#define WS_W3P   28672      // u64[432]
#define WS_WFCP  32768      // u64[205]
#define WS_A2    40960      // u64[4096*154] = 5,046,272 ; reused as A3 u64[4096*108]
#define WS_P1    5087232    // u8[4096*8448] = 34,603,008 ; reused as C2T s16[48*4096*108] = 42,467,328
#define WS_C2T   5087232
#define WS_P3T   5087232    // s16[48*4096*54] = 21,233,664 (overlays c2T after kM3)
#define WS_P3B   26320896   // s16[4096*48*54] = 21,233,664  -> ends 47,554,560
#define WS_A3    40960

// ---------------- d_out offsets (floats) ----------------
#define OUT_OFF 0
#define XB1_OFF 20480
#define XB2_OFF 8867840
#define XB3_OFF 39145472
#define FB_OFF  60379136

__device__ __forceinline__ float fsign(float v) {
    return (v > 0.0f) ? 1.0f : ((v < 0.0f) ? -1.0f : 0.0f);
}
__device__ __forceinline__ int sh16(int v, int h) {
    return h ? (v >> 16) : (int)(short)v;
}

// ---- weight binarize+pack, stats zero ----
__global__ __launch_bounds__(512)
void kw_pack(const float* __restrict__ w1, const float* __restrict__ w2,
             const float* __restrict__ w3, const float* __restrict__ wfc,
             u32* __restrict__ W1Q, u64* __restrict__ W2P, u64* __restrict__ W3P,
             u64* __restrict__ WFCP, long long* __restrict__ stats) {
    int t = threadIdx.x;
    for (int i = t; i < 2304; i += 512) stats[i] = 0;
    if (t < 48) {
        u16 m1[9];
        #pragma unroll
        for (int p = 0; p < 9; ++p) {
            u16 m = 0;
            for (int c = 0; c < 12; ++c)
                if (w1[t*108 + c*9 + p] > 0.0f) m |= (u16)(1u << c);
            m1[p] = m;
        }
        #pragma unroll
        for (int j = 0; j < 4; ++j)
            W1Q[t*5 + j] = (u32)m1[2*j] | ((u32)m1[2*j+1] << 16);
        W1Q[t*5 + 4] = (u32)m1[8];
    }
    if (t < 432) {
        int oc = t / 9, p = t % 9;
        u64 m2 = 0, m3 = 0;
        for (int c = 0; c < 48; ++c) {
            if (w2[oc*432 + c*9 + p] > 0.0f) m2 |= (1ull << c);
            if (w3[oc*432 + c*9 + p] > 0.0f) m3 |= (1ull << c);
        }
        W2P[t] = m2;
        W3P[t] = m3;
    }
    if (t < 205) {
        int o = t / 41, j = t % 41;
        u64 m = 0;
        for (int l = 0; l < 64; ++l) {
            int k = j*64 + l;
            if (k < 2592 && wfc[o*2592 + k] > 0.0f) m |= (1ull << l);
        }
        WFCP[t] = m;
    }
}

// ---- BN consts from integer stats ----
__global__ __launch_bounds__(64)
void kbn(const float* __restrict__ g, const float* __restrict__ bb,
         const long long* __restrict__ st, float* __restrict__ cst, float Nf) {
    int t = threadIdx.x;
    if (t < 48) {
        long long s = 0, q = 0;
        #pragma unroll
        for (int k = 0; k < 8; ++k) { s += st[t*8 + k]; q += st[(48 + t)*8 + k]; }
        double N = (double)Nf;
        double mean = (double)s / N;
        double var  = (double)q / N - mean*mean;
        double scale = (double)g[t] / sqrt(var + 1e-5);
        cst[t]      = (float)scale;
        cst[48 + t] = (float)((double)bb[t] - mean*scale);
    }
}

// ---- binarize x -> xb1 (float4), conv1 (pad1), pool -> P1, stats1 ----
__global__ __launch_bounds__(192)
void k1(const float* __restrict__ x, const u32* __restrict__ W1Q,
        float* __restrict__ dout, u8* __restrict__ P1g, u64* __restrict__ stats) {
    __shared__ u8 bitsb[2160];
    __shared__ u16 As[180];
    __shared__ int cmap[2304];   // s8 [48][12][16]
    __shared__ int2 part[192];
    int t = threadIdx.x, b = blockIdx.x;
    {
        const float4* xp = (const float4*)(x + (size_t)b*2160);
        float4* xo = (float4*)(dout + XB1_OFF + (size_t)b*2160);
        for (int j = t; j < 540; j += 192) {
            float4 v = xp[j];
            float4 o;
            o.x = fsign(v.x); o.y = fsign(v.y); o.z = fsign(v.z); o.w = fsign(v.w);
            xo[j] = o;
            bitsb[4*j]   = v.x > 0.0f;
            bitsb[4*j+1] = v.y > 0.0f;
            bitsb[4*j+2] = v.z > 0.0f;
            bitsb[4*j+3] = v.w > 0.0f;
        }
    }
    __syncthreads();
    if (t < 180) {
        u16 m = 0;
        #pragma unroll
        for (int c = 0; c < 12; ++c)
            m |= ((u16)bitsb[c*180 + t]) << c;
        As[t] = m;
    }
    __syncthreads();
    if (t < 180) {
        int y = t / 15, xx = t % 15;
        u16 tap[9], msk[9];
        int nv = 0;
        #pragma unroll
        for (int ky = 0; ky < 3; ++ky) {
            #pragma unroll
            for (int kx = 0; kx < 3; ++kx) {
                int yy = y + ky - 1, xc = xx + kx - 1;
                bool v = (yy >= 0 && yy < 12 && xc >= 0 && xc < 15);
                int yl = min(max(yy, 0), 11), xl = min(max(xc, 0), 14);
                tap[ky*3+kx] = As[yl*15 + xl];
                msk[ky*3+kx] = v ? (u16)0xFFFF : (u16)0;
                nv += v ? 12 : 0;
            }
        }
        u32 tq[5], mq[5];
        #pragma unroll
        for (int j = 0; j < 4; ++j) {
            tq[j] = (u32)tap[2*j] | ((u32)tap[2*j+1] << 16);
            mq[j] = (u32)msk[2*j] | ((u32)msk[2*j+1] << 16);
        }
        tq[4] = tap[8]; mq[4] = msk[8];
        s8* cb = (s8*)cmap;
        #pragma unroll 4
        for (int oc = 0; oc < 48; ++oc) {
            int acc = 0;
            #pragma unroll
            for (int j = 0; j < 5; ++j)
                acc += __popc((tq[j] ^ W1Q[oc*5 + j]) & mq[j]);
            cb[oc*192 + y*16 + xx] = (s8)(nv - 2*acc);
        }
    }
    __syncthreads();
    {
        int c = t >> 2, q = t & 3;
        int r0 = 3*q, nr = (q < 3) ? 3 : 2;
        int rowv[4][4];
        #pragma unroll
        for (int j = 0; j < 4; ++j)
            if (j <= nr) {
                #pragma unroll
                for (int i = 0; i < 4; ++i)
                    rowv[j][i] = cmap[c*48 + (r0 + j)*4 + i];
            }
        int sum = 0, sq = 0;
        u8* gp = P1g + (size_t)b*8448 + c*176;
        #pragma unroll
        for (int pr = 0; pr < 3; ++pr) {
            if (pr < nr) {
                int o0 = 0, o1 = 0, o2 = 0, o3 = 0;
                #pragma unroll
                for (int k = 0; k < 14; ++k) {
                    int a0 = (int)(s8)(rowv[pr][k>>2] >> (8*(k&3)));
                    int a1 = (int)(s8)(rowv[pr][(k+1)>>2] >> (8*((k+1)&3)));
                    int b0 = (int)(s8)(rowv[pr+1][k>>2] >> (8*(k&3)));
                    int b1 = (int)(s8)(rowv[pr+1][(k+1)>>2] >> (8*((k+1)&3)));
                    int mx = max(max(a0, a1), max(b0, b1));
                    sum += mx; sq += mx*mx;
                    int shl = 8*(k&3);
                    if ((k>>2) == 0) o0 |= (mx & 255) << shl;
                    else if ((k>>2) == 1) o1 |= (mx & 255) << shl;
                    else if ((k>>2) == 2) o2 |= (mx & 255) << shl;
                    else o3 |= (mx & 255) << shl;
                }
                *((int4*)(gp + (r0 + pr)*16)) = make_int4(o0, o1, o2, o3);
            }
        }
        part[t] = make_int2(sum, sq);
    }
    __syncthreads();
    if (t < 48) {
        int s = 0, q = 0;
        #pragma unroll
        for (int k = 0; k < 4; ++k) { s += part[t*4+k].x; q += part[t*4+k].y; }
        int slot = b & 7;
        atomicAdd(&stats[t*8 + slot],        (u64)(long long)s);
        atomicAdd(&stats[(48 + t)*8 + slot], (u64)(long long)q);
    }
}

// ---- kM2: A2 masks, flat over (b,154) ----
__global__ __launch_bounds__(256)
void kM2(const float* __restrict__ cst, const u8* __restrict__ P1g,
         u64* __restrict__ A2) {
    __shared__ float sc[48], sh[48];
    int t = threadIdx.x;
    if (t < 48) sc[t] = cst[t];
    else if (t < 96) sh[t-48] = cst[t];
    __syncthreads();
    int g = blockIdx.x*256 + t;          // < 630784
    int b = g / 154, s = g - 154*b;
    int row = s / 14, px = s - 14*row;
    const u8* pb = P1g + (size_t)b*8448 + row*16 + px;
    u64 m = 0;
    #pragma unroll
    for (int c = 0; c < 48; ++c)
        if (sc[c]*(float)(s8)pb[c*176] + sh[c] > 0.0f) m |= (1ull << c);
    A2[g] = m;
}

// ---- kS2: stream xb2 (float4) from P1 + BN1 consts ----
__global__ __launch_bounds__(256)
void kS2(const float* __restrict__ cst, const u8* __restrict__ P1g,
         float* __restrict__ dout) {
    __shared__ float sc[48], sh[48];
    int t = threadIdx.x;
    if (t < 48) sc[t] = cst[t];
    else if (t < 96) sh[t-48] = cst[t];
    __syncthreads();
    float4* xo = (float4*)(dout + XB2_OFF);
    int gid = blockIdx.x*256 + t;
    for (int j = gid; j < 7569408; j += 1048576) {   // 4096*7392/4
        int base = 4*j;
        int b = base / 7392;
        int u = base - 7392*b;
        const u8* pb = P1g + (size_t)b*8448;
        float r[4];
        #pragma unroll
        for (int k = 0; k < 4; ++k) {
            int uk = u + k;
            int c = uk / 154;
            int s = uk - 154*c;
            int row = s / 14;
            int px = s - 14*row;
            int v = (int)(s8)pb[c*176 + row*16 + px];
            r[k] = fsign(sc[c]*(float)v + sh[c]);
        }
        float4 o; o.x = r[0]; o.y = r[1]; o.z = r[2]; o.w = r[3];
        xo[j] = o;
    }
}

// ---- kCv2: conv2, flat over (b,108), 48 ch -> c2T[48][4096][108] ----
__global__ __launch_bounds__(256)
void kCv2(const u64* __restrict__ A2, const u64* __restrict__ W2,
          short* __restrict__ C2T) {
    __shared__ u64 W2s[432];
    int t = threadIdx.x;
    for (int i = t; i < 432; i += 256) W2s[i] = W2[i];
    __syncthreads();
    int g = blockIdx.x*256 + t;          // < 442368
    int b = g / 108, s = g - 108*b;
    int oy = s / 12, ox = s - 12*oy;
    const u64* ab = A2 + (size_t)b*154;
    u64 tap[9];
    #pragma unroll
    for (int ky = 0; ky < 3; ++ky)
        #pragma unroll
        for (int kx = 0; kx < 3; ++kx)
            tap[ky*3+kx] = ab[(oy+ky)*14 + ox + kx];
    #pragma unroll 4
    for (int oc = 0; oc < 48; ++oc) {
        int acc = 0;
        #pragma unroll
        for (int k = 0; k < 9; ++k)
            acc += __popcll(tap[k] ^ W2s[oc*9 + k]);
        C2T[(size_t)oc*442368 + b*108 + s] = (short)(432 - 2*acc);
    }
}

// ---- kSt: per-channel (sum,sq) over a contiguous channel plane ----
__global__ __launch_bounds__(256)
void kSt(const short* __restrict__ src, int perChan,
         long long* __restrict__ stats, int base) {
    __shared__ long long redS[4], redQ[4];
    int t = threadIdx.x, c = blockIdx.x;
    const int* p = (const int*)(src + (size_t)c*perChan);
    int n2 = perChan >> 1;
    int sum = 0, sq = 0;
    for (int j = t; j < n2; j += 256) {
        int v2 = p[j];
        int lo = (int)(short)v2, hi = v2 >> 16;
        sum += lo + hi; sq += lo*lo + hi*hi;
    }
    long long ls = sum, lq = sq;
    #pragma unroll
    for (int off = 32; off >= 1; off >>= 1) {
        ls += __shfl_down(ls, off);
        lq += __shfl_down(lq, off);
    }
    int wv = t >> 6, ln = t & 63;
    if (ln == 0) { redS[wv] = ls; redQ[wv] = lq; }
    __syncthreads();
    if (t == 0) {
        long long S = redS[0]+redS[1]+redS[2]+redS[3];
        long long Q = redQ[0]+redQ[1]+redQ[2]+redQ[3];
        stats[(base + c)*8]      = S;
        stats[(base + 48 + c)*8] = Q;
    }
}

// ---- kX3: stream xb3 (float4) from c2T + BN2 consts ----
__global__ __launch_bounds__(256)
void kX3(const float* __restrict__ cst, const short* __restrict__ C2T,
         float* __restrict__ dout) {
    __shared__ float sc[48], sh[48];
    int t = threadIdx.x;
    if (t < 48) sc[t] = cst[t];
    else if (t < 96) sh[t-48] = cst[t];
    __syncthreads();
    int g = blockIdx.x*256 + t;          // < 5308416 = 4096*1296
    int b = g / 1296, i4 = g - 1296*b;
    int c = i4 / 27, s4 = i4 - 27*c;
    const short* p = C2T + (size_t)c*442368 + b*108 + s4*4;
    short4 v4 = *(const short4*)p;
    float4 o;
    o.x = fsign(sc[c]*(float)v4.x + sh[c]);
    o.y = fsign(sc[c]*(float)v4.y + sh[c]);
    o.z = fsign(sc[c]*(float)v4.z + sh[c]);
    o.w = fsign(sc[c]*(float)v4.w + sh[c]);
    ((float4*)(dout + XB3_OFF))[(size_t)b*1296 + i4] = o;
}

// ---- kM3: A3 masks, flat over (b,108) ----
__global__ __launch_bounds__(256)
void kM3(const float* __restrict__ cst, const short* __restrict__ C2T,
         u64* __restrict__ A3) {
    __shared__ float sc[48], sh[48];
    int t = threadIdx.x;
    if (t < 48) sc[t] = cst[t];
    else if (t < 96) sh[t-48] = cst[t];
    __syncthreads();
    int g = blockIdx.x*256 + t;          // < 442368
    int b = g / 108, s = g - 108*b;
    u64 m = 0;
    #pragma unroll
    for (int c = 0; c < 48; ++c) {
        short v = C2T[(size_t)c*442368 + b*108 + s];
        if (sc[c]*(float)v + sh[c] > 0.0f) m |= (1ull << c);
    }
    A3[g] = m;
}

// ---- kCv3P: conv3 + pool fused, flat over (b,2,54), 24 ch each ----
__global__ __launch_bounds__(256)
void kCv3P(const u64* __restrict__ A3, const u64* __restrict__ W3,
           short* __restrict__ P3T, short* __restrict__ P3B) {
    __shared__ u64 W3s[432];
    int t = threadIdx.x;
    for (int i = t; i < 432; i += 256) W3s[i] = W3[i];
    __syncthreads();
    int g = blockIdx.x*256 + t;          // < 442368 = 4096*108
    int b = g / 108, r = g - 108*b;
    int grp = r / 54, s = r - 54*grp;
    int ocb = grp*24;
    int py = s / 9, px = s - 9*py;
    const u64* ab = A3 + (size_t)b*108;
    u64 tp[4][4];
    #pragma unroll
    for (int j = 0; j < 4; ++j)
        #pragma unroll
        for (int i = 0; i < 4; ++i)
            tp[j][i] = ab[(py+j)*12 + px + i];
    for (int oc = ocb; oc < ocb + 24; ++oc) {
        int rs[4][2];
        #pragma unroll
        for (int j = 0; j < 4; ++j) {
            #pragma unroll
            for (int sx = 0; sx < 2; ++sx) {
                int a = 0;
                #pragma unroll
                for (int kx = 0; kx < 3; ++kx)
                    a += __popcll(tp[j][kx+sx] ^ W3s[oc*9 + 0*3 + kx]);
                rs[j][sx] = a;
            }
        }
        // rows above used ky=0 weights only for row j as input row (py+j).
        // conv(sy,sx) needs Σ_ky popcll(tp[sy+ky][kx+sx] ^ w[ky*3+kx]) — redo properly:
        int c00, c01, c10, c11;
        {
            int a00=0,a01=0,a10=0,a11=0;
            #pragma unroll
            for (int ky = 0; ky < 3; ++ky) {
                #pragma unroll
                for (int kx = 0; kx < 3; ++kx) {
                    u64 w = W3s[oc*9 + ky*3 + kx];
                    a00 += __popcll(tp[ky][kx]     ^ w);
                    a01 += __popcll(tp[ky][kx+1]   ^ w);
                    a10 += __popcll(tp[ky+1][kx]   ^ w);
                    a11 += __popcll(tp[ky+1][kx+1] ^ w);
                }
            }
            c00 = 432 - 2*a00; c01 = 432 - 2*a01;
            c10 = 432 - 2*a10; c11 = 432 - 2*a11;
        }
        (void)rs;
        int mx = max(max(c00, c01), max(c10, c11));
        P3T[(size_t)oc*221184 + b*54 + s] = (short)mx;
        P3B[(size_t)b*2592 + oc*54 + s]   = (short)mx;
    }
}

// ---- kFB: stream fb (float4) from P3B + BN3 consts ----
__global__ __launch_bounds__(256)
void kFB(const float* __restrict__ cst, const short* __restrict__ P3B,
         float* __restrict__ dout) {
    __shared__ float sc[48], sh[48];
    int t = threadIdx.x;
    if (t < 48) sc[t] = cst[t];
    else if (t < 96) sh[t-48] = cst[t];
    __syncthreads();
    int g = blockIdx.x*256 + t;          // < 2654208 = 4096*648
    int b = g / 648, i4 = g - 648*b;
    int idx = 4*i4;
    const short* p = P3B + (size_t)b*2592 + idx;
    short4 v4 = *(const short4*)p;
    int c0 = idx/54, c1 = (idx+1)/54, c2 = (idx+2)/54, c3 = (idx+3)/54;
    float4 o;
    o.x = fsign(sc[c0]*(float)v4.x + sh[c0]);
    o.y = fsign(sc[c1]*(float)v4.y + sh[c1]);
    o.z = fsign(sc[c2]*(float)v4.z + sh[c2]);
    o.w = fsign(sc[c3]*(float)v4.w + sh[c3]);
    ((float4*)(dout + FB_OFF))[(size_t)b*648 + i4] = o;
}

// ---- kFC: per-wave FC via ballot ----
__global__ __launch_bounds__(256)
void kFC(const float* __restrict__ cst, const short* __restrict__ P3B,
         const u64* __restrict__ WFC, float* __restrict__ dout) {
    __shared__ float sc[48], sh[48];
    __shared__ u64 WFCs[205];
    int t = threadIdx.x;
    if (t < 48) sc[t] = cst[t];
    else if (t < 96) sh[t-48] = cst[t];
    if (t < 205) WFCs[t] = WFC[t];
    __syncthreads();
    int wv = t >> 6, ln = t & 63;
    int b = blockIdx.x*4 + wv;           // 1024 blocks -> 4096 images
    const short* p = P3B + (size_t)b*2592;
    u64 myword = 0;
    for (int w = 0; w < 41; ++w) {
        int k = w*64 + ln;
        bool pred = false;
        if (k < 2592) {
            int c = k / 54;
            pred = sc[c]*(float)p[k] + sh[c] > 0.0f;
        }
        u64 ball = __ballot(pred);
        if (ln == w) myword = ball;
    }
    #pragma unroll
    for (int o = 0; o < 5; ++o) {
        long long contrib = (ln < 41) ? (long long)__popcll(myword ^ WFCs[o*41 + ln]) : 0;
        #pragma unroll
        for (int off = 32; off >= 1; off >>= 1)
            contrib += __shfl_down(contrib, off);
        if (ln == 0) dout[OUT_OFF + b*5 + o] = (float)(2592 - 2*(int)contrib);
    }
}

extern "C" void kernel_launch(void* const* d_in, const int* in_sizes, int n_in,
                              void* d_out, int out_size, void* d_ws, size_t ws_size,
                              hipStream_t stream) {
    const float* x   = (const float*)d_in[0];
    const float* w1  = (const float*)d_in[1];
    const float* g1  = (const float*)d_in[2];
    const float* b1  = (const float*)d_in[3];
    const float* w2  = (const float*)d_in[4];
    const float* g2  = (const float*)d_in[5];
    const float* b2  = (const float*)d_in[6];
    const float* w3  = (const float*)d_in[7];
    const float* g3  = (const float*)d_in[8];
    const float* b3  = (const float*)d_in[9];
    const float* wfc = (const float*)d_in[10];
    float* out = (float*)d_out;
    char* ws = (char*)d_ws;

    long long* stats = (long long*)(ws + WS_STATS);
    float*     cst   = (float*)(ws + WS_CST);
    u32*       W1Q   = (u32*)(ws + WS_W1Q);
    u64*       W2P   = (u64*)(ws + WS_W2P);
    u64*       W3P   = (u64*)(ws + WS_W3P);
    u64*       WFCP  = (u64*)(ws + WS_WFCP);
    u64*       A2    = (u64*)(ws + WS_A2);
    u64*       A3    = (u64*)(ws + WS_A3);
    u8*        P1g   = (u8*)(ws + WS_P1);
    short*     C2T   = (short*)(ws + WS_C2T);
    short*     P3T   = (short*)(ws + WS_P3T);
    short*     P3B   = (short*)(ws + WS_P3B);

    hipLaunchKernelGGL(kw_pack, dim3(1),     dim3(512), 0, stream,
                       w1, w2, w3, wfc, W1Q, W2P, W3P, WFCP, stats);
    hipLaunchKernelGGL(k1,      dim3(NB),    dim3(192), 0, stream,
                       x, W1Q, out, P1g, (u64*)stats);
    hipLaunchKernelGGL(kbn,     dim3(1),     dim3(64),  0, stream,
                       g1, b1, stats, cst, 630784.0f);
    hipLaunchKernelGGL(kM2,     dim3(2464),  dim3(256), 0, stream, cst, P1g, A2);
    hipLaunchKernelGGL(kS2,     dim3(4096),  dim3(256), 0, stream, cst, P1g, out);
    hipLaunchKernelGGL(kCv2,    dim3(1728),  dim3(256), 0, stream, A2, W2P, C2T);
    hipLaunchKernelGGL(kSt,     dim3(48),    dim3(256), 0, stream,
                       C2T, 442368, stats, 96);
    hipLaunchKernelGGL(kbn,     dim3(1),     dim3(64),  0, stream,
                       g2, b2, stats + 96*8, cst + 96, 442368.0f);
    hipLaunchKernelGGL(kX3,     dim3(20736), dim3(256), 0, stream,
                       cst + 96, C2T, out);
    hipLaunchKernelGGL(kM3,     dim3(1728),  dim3(256), 0, stream,
                       cst + 96, C2T, A3);
    hipLaunchKernelGGL(kCv3P,   dim3(1728),  dim3(256), 0, stream,
                       A3, W3P, P3T, P3B);
    hipLaunchKernelGGL(kSt,     dim3(48),    dim3(256), 0, stream,
                       P3T, 221184, stats, 192);
    hipLaunchKernelGGL(kbn,     dim3(1),     dim3(64),  0, stream,
                       g3, b3, stats + 192*8, cst + 192, 221184.0f);
    hipLaunchKernelGGL(kFB,     dim3(10368), dim3(256), 0, stream,
                       cst + 192, P3B, out);
    hipLaunchKernelGGL(kFC,     dim3(1024),  dim3(256), 0, stream,
                       cst + 192, P3B, WFCP, out);
}